// Round 9
// baseline (88.115 us; speedup 1.0000x reference)
//
#include <hip/hip_runtime.h>
#include <math.h>

#define B_SZ 16
#define K_PTS 4096
#define ALPHA 1.1f
#define NB 256
#define BIGF 3.0e38f
#define EPSZ 1e-3f

// ws layout (bytes): pts4 float4[B][4096] @0 (1 MiB);
// perm uint[B][4096] @1048576; binb uint[B][4096] @1310720;
// hdr float[B][4] @1572864. total 1573120 B.
#define WS_PERM_OFF 1048576
#define WS_BINB_OFF 1310720
#define WS_HDR_OFF  1572864
#define WS_NEEDED   1573120

__device__ __forceinline__ void insert2(float d, float& m0, float& m1) {
    m1 = __builtin_amdgcn_fmed3f(d, m0, m1);
    m0 = fminf(d, m0);
}
__device__ __forceinline__ void insert3(float d, float& m0, float& m1, float& m2) {
    m2 = __builtin_amdgcn_fmed3f(d, m1, m2);
    m1 = __builtin_amdgcn_fmed3f(d, m0, m1);
    m0 = fminf(d, m0);
}

// Setup: per batch, counting-sort points into NB z-bins. Parallel prefix scan
// (Hillis-Steele). Within-bin scatter order is nondeterministic (atomics) but
// downstream results are order-independent exact min-set selections.
__global__ __launch_bounds__(1024) void sor_setup(
    const float* __restrict__ x, float4* __restrict__ pts4,
    unsigned* __restrict__ perm, unsigned* __restrict__ binb,
    float* __restrict__ hdr)
{
    __shared__ unsigned hist[NB];
    __shared__ unsigned scn[NB];
    __shared__ unsigned cur[NB];
    __shared__ float redmin[16], redmax[16];
    __shared__ float sh_zmin, sh_invw;

    const int b = blockIdx.x;
    const int tid = threadIdx.x;
    const float* xb = x + (size_t)b * K_PTS * 3;

    float z[4];
    float zmn = BIGF, zmx = -BIGF;
    #pragma unroll
    for (int k = 0; k < 4; ++k) {
        z[k] = xb[(tid + k * 1024) * 3 + 2];
        zmn = fminf(zmn, z[k]);
        zmx = fmaxf(zmx, z[k]);
    }
    #pragma unroll
    for (int off = 32; off > 0; off >>= 1) {
        zmn = fminf(zmn, __shfl_down(zmn, off, 64));
        zmx = fmaxf(zmx, __shfl_down(zmx, off, 64));
    }
    if ((tid & 63) == 0) { redmin[tid >> 6] = zmn; redmax[tid >> 6] = zmx; }
    if (tid < NB) hist[tid] = 0;
    __syncthreads();
    if (tid == 0) {
        float mn = redmin[0], mx = redmax[0];
        for (int wv = 1; wv < 16; ++wv) {
            mn = fminf(mn, redmin[wv]);
            mx = fmaxf(mx, redmax[wv]);
        }
        const float rng = fmaxf(mx - mn, 1e-6f);
        const float w = rng * (1.0f / NB);
        sh_zmin = mn;
        sh_invw = 1.0f / w;
        hdr[b * 4 + 0] = mn;
        hdr[b * 4 + 1] = w;
        hdr[b * 4 + 2] = 1.0f / w;
    }
    __syncthreads();
    const float zmin = sh_zmin, invw = sh_invw;

    int kb[4];
    #pragma unroll
    for (int k = 0; k < 4; ++k) {
        int kk = (int)((z[k] - zmin) * invw);
        kk = min(NB - 1, max(0, kk));
        kb[k] = kk;
        atomicAdd(&hist[kk], 1u);
    }
    __syncthreads();
    // inclusive scan of hist -> scn
    if (tid < NB) scn[tid] = hist[tid];
    __syncthreads();
    for (int off = 1; off < NB; off <<= 1) {
        unsigned v = 0;
        if (tid < NB) { v = scn[tid]; if (tid >= off) v += scn[tid - off]; }
        __syncthreads();
        if (tid < NB) scn[tid] = v;
        __syncthreads();
    }
    if (tid < NB) cur[tid] = 0;
    __syncthreads();

    #pragma unroll
    for (int k = 0; k < 4; ++k) {
        const int p = tid + k * 1024;
        const int kk = kb[k];
        const unsigned start = scn[kk] - hist[kk];   // exclusive prefix
        const unsigned pos = start + atomicAdd(&cur[kk], 1u);
        const float a0 = xb[p * 3 + 0];
        const float a1 = xb[p * 3 + 1];
        const float a2 = z[k];
        pts4[(size_t)b * K_PTS + pos] = make_float4(a0, a1, a2, a0 * a0 + a1 * a1 + a2 * a2);
        perm[(size_t)b * K_PTS + pos] = (unsigned)p;
        binb[(size_t)b * K_PTS + pos] = (unsigned)kk;
    }
}

// ---- search: NCH=2 chains/thread, up/down roles, manual LDS pipeline ----
// grid (16 kb, 16 b) x 256 thr. Block waves: (kb,up),(kb,down),(kb+16,up),
// (kb+16,down) - pairs dense/sparse ranges for balance. Wave covers 128
// consecutive z-sorted positions (chain0: P..P+63, chain1: P+64..P+127).
// UP: j >= i, top-3 incl self (dropped at merge). DOWN: j < i, top-2.
// Candidate stream: static 64-pt groups, 2x8 ping-pong register buffering;
// release between groups via conservative bin-edge bounds (exact).

#define LD8(BUF, JB) { _Pragma("unroll") for (int t = 0; t < 8; ++t) BUF[t] = pts[(JB) + t]; }

#define C_UP_G(BUF, JB) { _Pragma("unroll") for (int t = 0; t < 8; ++t) { \
    const float4 pj = BUF[t]; const int j = (JB) + t; \
    float u0 = fmaf(k0z, pj.z, pj.w); u0 = fmaf(k0y, pj.y, u0); float d0 = fmaf(k0x, pj.x, u0); \
    d0 = (j >= i0) ? d0 : BIGF; insert3(d0, a0, a1, a2); \
    float u1 = fmaf(k1z, pj.z, pj.w); u1 = fmaf(k1y, pj.y, u1); float d1 = fmaf(k1x, pj.x, u1); \
    d1 = (j >= i1) ? d1 : BIGF; insert3(d1, b0, b1, b2); } }

#define C_UP_P(BUF, JB) { _Pragma("unroll") for (int t = 0; t < 8; ++t) { \
    const float4 pj = BUF[t]; \
    float u0 = fmaf(k0z, pj.z, pj.w); u0 = fmaf(k0y, pj.y, u0); float d0 = fmaf(k0x, pj.x, u0); \
    insert3(d0, a0, a1, a2); \
    float u1 = fmaf(k1z, pj.z, pj.w); u1 = fmaf(k1y, pj.y, u1); float d1 = fmaf(k1x, pj.x, u1); \
    insert3(d1, b0, b1, b2); } }

#define C_DN_G(BUF, JB) { _Pragma("unroll") for (int t = 0; t < 8; ++t) { \
    const float4 pj = BUF[t]; const int j = (JB) + t; \
    float u0 = fmaf(k0z, pj.z, pj.w); u0 = fmaf(k0y, pj.y, u0); float d0 = fmaf(k0x, pj.x, u0); \
    d0 = (j < i0) ? d0 : BIGF; insert2(d0, a0, a1); \
    float u1 = fmaf(k1z, pj.z, pj.w); u1 = fmaf(k1y, pj.y, u1); float d1 = fmaf(k1x, pj.x, u1); \
    d1 = (j < i1) ? d1 : BIGF; insert2(d1, b0, b1); } }

#define C_DN_P(BUF, JB) { _Pragma("unroll") for (int t = 0; t < 8; ++t) { \
    const float4 pj = BUF[t]; \
    float u0 = fmaf(k0z, pj.z, pj.w); u0 = fmaf(k0y, pj.y, u0); float d0 = fmaf(k0x, pj.x, u0); \
    insert2(d0, a0, a1); \
    float u1 = fmaf(k1z, pj.z, pj.w); u1 = fmaf(k1y, pj.y, u1); float d1 = fmaf(k1x, pj.x, u1); \
    insert2(d1, b0, b1); } }

#define GROUP(JB, C) { float4 bA[8], bB[8]; \
    LD8(bA, (JB));      LD8(bB, (JB) + 8); \
    C(bA, (JB));        LD8(bA, (JB) + 16); \
    C(bB, (JB) + 8);    LD8(bB, (JB) + 24); \
    C(bA, (JB) + 16);   LD8(bA, (JB) + 32); \
    C(bB, (JB) + 24);   LD8(bB, (JB) + 40); \
    C(bA, (JB) + 32);   LD8(bA, (JB) + 48); \
    C(bB, (JB) + 40);   LD8(bB, (JB) + 56); \
    C(bA, (JB) + 48);   C(bB, (JB) + 56); }

__global__ __launch_bounds__(256, 1) void sor_search(
    const float4* __restrict__ pts4, const unsigned* __restrict__ perm,
    const unsigned* __restrict__ binb, const float* __restrict__ hdr,
    float* __restrict__ value)
{
    __shared__ float4 pts[K_PTS];      // 64 KiB
    __shared__ float zfl[64], zcl[64];
    __shared__ float2 dnw[2][128];

    const int b = blockIdx.y;
    const int kb = blockIdx.x;
    const int tid = threadIdx.x;

    #pragma unroll
    for (int it = 0; it < 16; ++it) {
        const int idx = tid + it * 256;
        pts[idx] = pts4[(size_t)b * K_PTS + idx];
    }
    const float zmin = hdr[b * 4 + 0];
    const float w    = hdr[b * 4 + 1];
    if (tid < 64) {
        // all points at position >= g*64 have z >= zfl[g];
        // all points at position <= g*64+63 have z <= zcl[g].
        zfl[tid] = zmin + (float)binb[(size_t)b * K_PTS + tid * 64] * w;
        zcl[tid] = zmin + (float)(binb[(size_t)b * K_PTS + tid * 64 + 63] + 1u) * w;
    }
    __syncthreads();

    const int lane = tid & 63;
    const int wv = tid >> 6;
    const int hi = wv >> 1;            // 0: range kb, 1: range kb+16
    const int role = wv & 1;           // 0 = up, 1 = down
    const int ridx = kb + hi * 16;
    const int P = ridx * 128;
    const int g0 = ridx * 2;
    const int i0 = P + lane;
    const int i1 = P + 64 + lane;

    const float4 q0 = pts[i0];
    const float4 q1 = pts[i1];
    const float k0x = -2.0f * q0.x, k0y = -2.0f * q0.y, k0z = -2.0f * q0.z;
    const float k1x = -2.0f * q1.x, k1y = -2.0f * q1.y, k1z = -2.0f * q1.z;
    const float w0v = q0.w, w1v = q1.w, z0v = q0.z, z1v = q1.z;

    float a0 = BIGF, a1 = BIGF, a2 = BIGF;
    float b0 = BIGF, b1 = BIGF, b2 = BIGF;

    if (role == 0) {
        GROUP(g0 * 64, C_UP_G);
        GROUP(g0 * 64 + 64, C_UP_G);
        bool act0 = true, act1 = true;
        for (int g = g0 + 2; g < 64; ++g) {
            const float zf = zfl[g];
            const float gp0 = fmaxf(zf - z0v - EPSZ, 0.0f);
            const float gp1 = fmaxf(zf - z1v - EPSZ, 0.0f);
            act0 = act0 && (gp0 * gp0 <= a2 + w0v);
            act1 = act1 && (gp1 * gp1 <= b2 + w1v);
            if (__ballot(act0 || act1) == 0ull) break;
            GROUP(g * 64, C_UP_P);
        }
    } else {
        GROUP(g0 * 64 + 64, C_DN_G);
        GROUP(g0 * 64, C_DN_G);
        bool act0 = true, act1 = true;
        for (int g = g0 - 1; g >= 0; --g) {
            const float zc = zcl[g];
            const float gp0 = fmaxf(z0v - zc - EPSZ, 0.0f);
            const float gp1 = fmaxf(z1v - zc - EPSZ, 0.0f);
            act0 = act0 && (gp0 * gp0 <= a1 + w0v);
            act1 = act1 && (gp1 * gp1 <= b1 + w1v);
            if (__ballot(act0 || act1) == 0ull) break;
            GROUP(g * 64, C_DN_P);
        }
        dnw[hi][lane]      = make_float2(a0, a1);
        dnw[hi][64 + lane] = make_float2(b0, b1);
    }
    __syncthreads();

    if (role == 0) {
        // chain0: 2NN = two smallest of {up.m1, up.m2, dn.m0, dn.m1}
        const float2 dA = dnw[hi][lane];
        float M0 = BIGF, M1 = BIGF;
        insert2(a1, M0, M1); insert2(a2, M0, M1);
        insert2(dA.x, M0, M1); insert2(dA.y, M0, M1);
        const unsigned o0 = perm[(size_t)b * K_PTS + i0];
        value[(size_t)b * K_PTS + o0] = ((M0 + w0v) + (M1 + w0v)) * 0.5f;
        // chain1
        const float2 dB = dnw[hi][64 + lane];
        float N0 = BIGF, N1 = BIGF;
        insert2(b1, N0, N1); insert2(b2, N0, N1);
        insert2(dB.x, N0, N1); insert2(dB.y, N0, N1);
        const unsigned o1 = perm[(size_t)b * K_PTS + i1];
        value[(size_t)b * K_PTS + o1] = ((N0 + w1v) + (N1 + w1v)) * 0.5f;
    }
}

// One block per batch: mean/std(ddof=1) -> threshold -> mask + zeroed points.
__global__ __launch_bounds__(1024) void sor_mask_kernel(
    const float* __restrict__ x, float* __restrict__ out)
{
    const int b = blockIdx.x;
    const int tid = threadIdx.x;
    float* value = out + (size_t)B_SZ * K_PTS * 3;
    float* selpc = out;

    __shared__ float red[16];
    __shared__ float sh_mean, sh_thr;

    float v[4];
    float s = 0.0f;
    #pragma unroll
    for (int k = 0; k < 4; ++k) {
        v[k] = value[b * K_PTS + tid + k * 1024];
        s += v[k];
    }
    #pragma unroll
    for (int off = 32; off > 0; off >>= 1) s += __shfl_down(s, off, 64);
    if ((tid & 63) == 0) red[tid >> 6] = s;
    __syncthreads();
    if (tid == 0) {
        float t = 0.0f;
        for (int wv = 0; wv < 16; ++wv) t += red[wv];
        sh_mean = t * (1.0f / (float)K_PTS);
    }
    __syncthreads();
    const float mean = sh_mean;

    float q = 0.0f;
    #pragma unroll
    for (int k = 0; k < 4; ++k) { float dv = v[k] - mean; q += dv * dv; }
    #pragma unroll
    for (int off = 32; off > 0; off >>= 1) q += __shfl_down(q, off, 64);
    if ((tid & 63) == 0) red[tid >> 6] = q;
    __syncthreads();
    if (tid == 0) {
        float t = 0.0f;
        for (int wv = 0; wv < 16; ++wv) t += red[wv];
        sh_thr = mean + ALPHA * sqrtf(t / (float)(K_PTS - 1));
    }
    __syncthreads();
    const float thr = sh_thr;

    #pragma unroll
    for (int k = 0; k < 4; ++k) {
        const int i = tid + k * 1024;
        const bool keep = v[k] <= thr;
        value[b * K_PTS + i] = keep ? 1.0f : 0.0f;
        const size_t base = ((size_t)b * K_PTS + i) * 3;
        float x0 = x[base + 0];
        float x1 = x[base + 1];
        float x2 = x[base + 2];
        selpc[base + 0] = keep ? x0 : 0.0f;
        selpc[base + 1] = keep ? x1 : 0.0f;
        selpc[base + 2] = keep ? x2 : 0.0f;
    }
}

// ---- Fallback (round-1 structure) used only if d_ws is too small ----
__global__ __launch_bounds__(256) void sor_value_kernel(
    const float* __restrict__ x, float* __restrict__ value)
{
    __shared__ float4 pts[K_PTS];
    const int b = blockIdx.y;
    const float* xb = x + (size_t)b * K_PTS * 3;
    for (int p = threadIdx.x; p < K_PTS; p += 256) {
        float a0 = xb[p * 3 + 0];
        float a1 = xb[p * 3 + 1];
        float a2 = xb[p * 3 + 2];
        pts[p] = make_float4(a0, a1, a2, a0 * a0 + a1 * a1 + a2 * a2);
    }
    __syncthreads();
    const int i = blockIdx.x * 256 + threadIdx.x;
    const float4 pi = pts[i];
    float m0 = BIGF, m1 = BIGF, m2 = BIGF;
    #pragma unroll 8
    for (int j = 0; j < K_PTS; ++j) {
        float4 pj = pts[j];
        float dot = pi.x * pj.x + pi.y * pj.y + pi.z * pj.z;
        float d = (pi.w - 2.0f * dot) + pj.w;
        insert3(d, m0, m1, m2);
    }
    value[b * K_PTS + i] = 0.5f * (m1 + m2);
}

extern "C" void kernel_launch(void* const* d_in, const int* in_sizes, int n_in,
                              void* d_out, int out_size, void* d_ws, size_t ws_size,
                              hipStream_t stream)
{
    const float* x = (const float*)d_in[0];
    float* out = (float*)d_out;
    float* value = out + (size_t)B_SZ * K_PTS * 3;

    if (ws_size >= (size_t)WS_NEEDED) {
        float4* pts4 = (float4*)d_ws;
        unsigned* perm = (unsigned*)((char*)d_ws + WS_PERM_OFF);
        unsigned* binb = (unsigned*)((char*)d_ws + WS_BINB_OFF);
        float* hdr = (float*)((char*)d_ws + WS_HDR_OFF);

        sor_setup<<<B_SZ, 1024, 0, stream>>>(x, pts4, perm, binb, hdr);
        dim3 gS(16, B_SZ);   // (16,16) = 256 blocks
        sor_search<<<gS, 256, 0, stream>>>(pts4, perm, binb, hdr, value);
    } else {
        dim3 g1(K_PTS / 256, B_SZ);
        sor_value_kernel<<<g1, 256, 0, stream>>>(x, value);
    }
    sor_mask_kernel<<<B_SZ, 1024, 0, stream>>>(x, out);
}